// Round 1
// baseline (1458.308 us; speedup 1.0000x reference)
//
#include <hip/hip_runtime.h>

// GaussianMLP fused: h=relu(x@W_emb+b_emb); mean=h@W_mean+b_mean;
// logvar=h@W_logvar+b_logvar; z=mean+exp(0.5*logvar)*eps.
// B=524288, D_IN=128, D_H=256, D_OUT=128. Memory-bound (1.28 GB min traffic).

typedef __attribute__((ext_vector_type(8))) short short8;   // 8 bf16 = 4 VGPRs (MFMA A/B frag)
typedef __attribute__((ext_vector_type(4))) float f32x4;    // MFMA C/D frag

__device__ __forceinline__ unsigned short f2bf(float f) {
  union { float f; unsigned int u; } v; v.f = f;
  // round-to-nearest-even bf16 truncation (no NaN inputs here)
  return (unsigned short)((v.u + 0x7fffu + ((v.u >> 16) & 1u)) >> 16);
}

// ws layout: ws1 = Wb1t[256][128] bf16  (Wb1t[n][k] = W_emb[k][n])
//            ws2 = Wb2t[256][256] bf16  (n<128: W_mean[k][n]; n>=128: W_logvar[k][n-128])
__global__ void __launch_bounds__(256) prep_weights(
    const float* __restrict__ W_emb, const float* __restrict__ W_mean,
    const float* __restrict__ W_logvar, unsigned short* __restrict__ ws1,
    unsigned short* __restrict__ ws2) {
  int idx = blockIdx.x * 256 + threadIdx.x;
  if (idx < 32768) {                       // W_emb: (128,256) row-major, coalesced read
    int k = idx >> 8, n = idx & 255;
    ws1[n * 128 + k] = f2bf(W_emb[idx]);
  } else if (idx < 65536) {                // W_mean: (256,128)
    int i = idx - 32768;
    int k = i >> 7, n = i & 127;
    ws2[n * 256 + k] = f2bf(W_mean[i]);
  } else if (idx < 98304) {                // W_logvar: (256,128)
    int i = idx - 65536;
    int k = i >> 7, n = i & 127;
    ws2[(n + 128) * 256 + k] = f2bf(W_logvar[i]);
  }
}

// Block = 256 threads = 4 waves; each wave owns 32 rows end-to-end.
// MFMA 16x16x32 bf16 layouts (verified in guide, m89/m120):
//   A[m=lane&15][k=quad*8+j], B[k=quad*8+j][n=lane&15], C/D: col=lane&15, row=quad*4+reg
__global__ void __launch_bounds__(256, 2) gmlp_kernel(
    const float* __restrict__ x, const float* __restrict__ eps,
    const float* __restrict__ b_emb, const float* __restrict__ b_mean,
    const float* __restrict__ b_logvar,
    const unsigned short* __restrict__ wb1,  // [256][128] bf16, n-major
    const unsigned short* __restrict__ wb2,  // [256][256] bf16, n-major
    float* __restrict__ z, float* __restrict__ mn, float* __restrict__ lg) {
  constexpr int HPAD = 264;  // 256 + 8 bf16 pad: keeps 16B alignment, balances banks
  __shared__ unsigned short h_all[4][32][HPAD];  // 66 KB -> 2 blocks/CU
  const int tid = threadIdx.x;
  const int wv = tid >> 6, lane = tid & 63;
  const int l15 = lane & 15, quad = lane >> 4;
  unsigned short(*h_lds)[HPAD] = h_all[wv];

  const int row0 = blockIdx.x * 128 + wv * 32;

  // ---- preload x A-frags (fp32 global -> bf16 regs), held through layer 1
  short8 ax[2][4];
#pragma unroll
  for (int mt = 0; mt < 2; ++mt) {
    const float* xp = x + (row0 + mt * 16 + l15) * 128 + quad * 8;
#pragma unroll
    for (int ks = 0; ks < 4; ++ks) {
      f32x4 p0 = *(const f32x4*)(xp + ks * 32);
      f32x4 p1 = *(const f32x4*)(xp + ks * 32 + 4);
      short8 a;
      a[0] = (short)f2bf(p0[0]); a[1] = (short)f2bf(p0[1]);
      a[2] = (short)f2bf(p0[2]); a[3] = (short)f2bf(p0[3]);
      a[4] = (short)f2bf(p1[0]); a[5] = (short)f2bf(p1[1]);
      a[6] = (short)f2bf(p1[2]); a[7] = (short)f2bf(p1[3]);
      ax[mt][ks] = a;
    }
  }

  // ---- layer 1: h(32x256) = relu(x(32x128) @ W_emb(128x256) + b), in 4 n-chunks
  for (int c = 0; c < 4; ++c) {
    f32x4 acc[2][4];
#pragma unroll
    for (int t = 0; t < 4; ++t) {
      acc[0][t] = (f32x4){0.f, 0.f, 0.f, 0.f};
      acc[1][t] = (f32x4){0.f, 0.f, 0.f, 0.f};
    }
#pragma unroll
    for (int t = 0; t < 4; ++t) {
      const int nt = c * 4 + t;
      const unsigned short* wp = wb1 + (nt * 16 + l15) * 128 + quad * 8;
#pragma unroll
      for (int ks = 0; ks < 4; ++ks) {
        short8 b = *(const short8*)(wp + ks * 32);
        acc[0][t] = __builtin_amdgcn_mfma_f32_16x16x32_bf16(ax[0][ks], b, acc[0][t], 0, 0, 0);
        acc[1][t] = __builtin_amdgcn_mfma_f32_16x16x32_bf16(ax[1][ks], b, acc[1][t], 0, 0, 0);
      }
    }
    // epilogue: +bias, relu, cast bf16, store to LDS in [m][k]-contiguous layout
#pragma unroll
    for (int t = 0; t < 4; ++t) {
      const int nt = c * 4 + t;
      float bias = b_emb[nt * 16 + l15];
#pragma unroll
      for (int mt = 0; mt < 2; ++mt)
#pragma unroll
        for (int r = 0; r < 4; ++r) {
          float v = acc[mt][t][r] + bias;
          v = v > 0.f ? v : 0.f;
          h_lds[mt * 16 + quad * 4 + r][nt * 16 + l15] = f2bf(v);
        }
    }
  }

  __syncthreads();  // h visible (also orders the per-wave LDS write->read)

  // ---- layer 2: [mean|logvar](32x256) = h(32x256) @ Wb2t^T, fused epilogue
  for (int g = 0; g < 4; ++g) {  // col group: mean tiles {2g,2g+1}, logvar {8+2g,8+2g+1}
    f32x4 aM[2][2], aL[2][2];
#pragma unroll
    for (int s = 0; s < 2; ++s) {
      aM[0][s] = (f32x4){0.f, 0.f, 0.f, 0.f}; aM[1][s] = (f32x4){0.f, 0.f, 0.f, 0.f};
      aL[0][s] = (f32x4){0.f, 0.f, 0.f, 0.f}; aL[1][s] = (f32x4){0.f, 0.f, 0.f, 0.f};
    }
#pragma unroll
    for (int ks = 0; ks < 8; ++ks) {
      short8 h0 = *(const short8*)&h_lds[l15][ks * 32 + quad * 8];
      short8 h1 = *(const short8*)&h_lds[16 + l15][ks * 32 + quad * 8];
#pragma unroll
      for (int s = 0; s < 2; ++s) {
        const int ntm = 2 * g + s, ntl = 8 + 2 * g + s;
        short8 bm = *(const short8*)(wb2 + (ntm * 16 + l15) * 256 + ks * 32 + quad * 8);
        short8 bl = *(const short8*)(wb2 + (ntl * 16 + l15) * 256 + ks * 32 + quad * 8);
        aM[0][s] = __builtin_amdgcn_mfma_f32_16x16x32_bf16(h0, bm, aM[0][s], 0, 0, 0);
        aM[1][s] = __builtin_amdgcn_mfma_f32_16x16x32_bf16(h1, bm, aM[1][s], 0, 0, 0);
        aL[0][s] = __builtin_amdgcn_mfma_f32_16x16x32_bf16(h0, bl, aL[0][s], 0, 0, 0);
        aL[1][s] = __builtin_amdgcn_mfma_f32_16x16x32_bf16(h1, bl, aL[1][s], 0, 0, 0);
      }
    }
    // epilogue: bias, rsample, stores (fp32, 64B-coalesced per 16-lane group)
#pragma unroll
    for (int s = 0; s < 2; ++s) {
      const int col = (2 * g + s) * 16 + l15;  // 0..127
      float bm = b_mean[col], bl = b_logvar[col];
#pragma unroll
      for (int mt = 0; mt < 2; ++mt)
#pragma unroll
        for (int r = 0; r < 4; ++r) {
          const int row = row0 + mt * 16 + quad * 4 + r;
          float m_ = aM[mt][s][r] + bm;
          float l_ = aL[mt][s][r] + bl;
          float e = eps[row * 128 + col];
          float zz = m_ + __expf(0.5f * l_) * e;
          z[row * 128 + col] = zz;
          mn[row * 128 + col] = m_;
          lg[row * 128 + col] = l_;
        }
    }
  }
}

extern "C" void kernel_launch(void* const* d_in, const int* in_sizes, int n_in,
                              void* d_out, int out_size, void* d_ws, size_t ws_size,
                              hipStream_t stream) {
  const float* x        = (const float*)d_in[0];
  const float* eps      = (const float*)d_in[1];
  const float* W_emb    = (const float*)d_in[2];
  const float* b_emb    = (const float*)d_in[3];
  const float* W_mean   = (const float*)d_in[4];
  const float* b_mean   = (const float*)d_in[5];
  const float* W_logvar = (const float*)d_in[6];
  const float* b_logvar = (const float*)d_in[7];

  unsigned short* ws1 = (unsigned short*)d_ws;      // 64 KB
  unsigned short* ws2 = ws1 + 256 * 128;            // 128 KB

  const long BN = 524288L * 128L;
  float* z  = (float*)d_out;
  float* mn = z + BN;
  float* lg = mn + BN;

  prep_weights<<<384, 256, 0, stream>>>(W_emb, W_mean, W_logvar, ws1, ws2);
  gmlp_kernel<<<4096, 256, 0, stream>>>(x, eps, b_emb, b_mean, b_logvar,
                                        ws1, ws2, z, mn, lg);
}